// Round 15
// baseline (432.401 us; speedup 1.0000x reference)
//
#include <hip/hip_runtime.h>
#include <stdint.h>

#define BATCH 128
#define NAT   128
#define DIM   128
#define CP    17
#define MAXIT 20
#define STEP  0.2f      // 2 * R_LR
#define LMD   0.005f
#define NGRAD 900

typedef short bf16x8 __attribute__((ext_vector_type(8)));   // 8 bf16 (4 VGPR)
typedef float f32x16 __attribute__((ext_vector_type(16)));  // 32x32 C/D

#define SZ_RP (BATCH*CP*CP*NAT)     // 4,734,976 elems
#define SZ_RS (BATCH*DIM*DIM)       // 2,097,152 elems
// workspace byte offsets (all 16B-aligned). R = single bf16 plane.
#define O_RP   0
#define O_RSH  (O_RP + SZ_RP*2)
#define O_W2H  (O_RSH + SZ_RS*2)
#define O_W2L  (O_W2H + 64*512*2)
#define O_WTH  (O_W2L + 64*512*2)
#define O_WTL  (O_WTH + 128*256*2)
#define O_PART (O_WTL + 128*256*2)   // 2 banks x 2048 floats (parity dbuf)

#define GLOAD16(gp, lp) __builtin_amdgcn_global_load_lds( \
    (const __attribute__((address_space(1))) uint32_t*)(gp), \
    (__attribute__((address_space(3))) uint32_t*)(lp), 16, 0, 0)

// split fp32 -> hi/lo bf16 (RNE)
__device__ __forceinline__ void split2(float x, ushort& h, ushort& l) {
    uint32_t u = __float_as_uint(x);
    uint32_t hr = (u + 0x7FFFu + ((u >> 16) & 1u)) >> 16;
    h = (ushort)hr;
    float r = x - __uint_as_float(hr << 16);
    uint32_t u2 = __float_as_uint(r);
    l = (ushort)((u2 + 0x7FFFu + ((u2 >> 16) & 1u)) >> 16);
}
__device__ __forceinline__ float us2f(ushort u) {
    return __uint_as_float(((uint32_t)u) << 16);
}
__device__ __forceinline__ uint pk(ushort a, ushort b) {
    return (uint)a | ((uint)b << 16);
}
__device__ __forceinline__ ushort f2bf(float x) {   // RNE round to bf16
    uint32_t u = __float_as_uint(x);
    return (ushort)((u + 0x7FFFu + ((u >> 16) & 1u)) >> 16);
}

__global__ void kzero(uint4* __restrict__ rp) {
    int i = blockIdx.x * 256 + threadIdx.x;
    rp[i] = uint4{0u, 0u, 0u, 0u};   // R single plane
}

// WtT = W layout [n][256]; W2T[uv][ij*128+n]; both as hi/lo bf16 planes
__global__ void kprep(const float* __restrict__ W,
                      ushort* __restrict__ wth, ushort* __restrict__ wtl,
                      ushort* __restrict__ w2h, ushort* __restrict__ w2l) {
    int tid = blockIdx.x * 256 + threadIdx.x;   // 32768
    int n = tid >> 8, kk = tid & 255;
    ushort h, l; split2(W[tid], h, l);
    wth[tid] = h; wtl[tid] = l;
    int kx = kk >> 4, ky = kk & 15;
    int uv = (kx & 7) * 8 + (ky & 7);
    int k2 = ((kx >> 3) * 2 + (ky >> 3)) * 128 + n;
    w2h[uv * 512 + k2] = h; w2l[uv * 512 + k2] = l;
}

// t=0 shortcut: R==0 -> resid = img (single bf16 plane)
__global__ void kinit0(const float* __restrict__ img, ushort* __restrict__ rsh) {
    int t8 = (blockIdx.x * 256 + threadIdx.x) * 8;
    uint hw[4];
#pragma unroll
    for (int v = 0; v < 2; ++v) {
        float4 im = *(const float4*)&img[t8 + v * 4];
        hw[v*2+0] = pk(f2bf(im.x), f2bf(im.y));
        hw[v*2+1] = pk(f2bf(im.z), f2bf(im.w));
    }
    *(uint4*)&rsh[t8] = uint4{hw[0],hw[1],hw[2],hw[3]};
}

// resid kconvt: pure-bf16 GEMM C[m=cell,uv] = R[m,512] x W2hi^T. UNGATED.
// 8 waves = 4 output quadrants x 2 K-halves (even/odd chunks); pair-staged
// 4 LDS bufs, counted vmcnt; LDS reduce of the two K-half accumulators.
__global__ __launch_bounds__(512, 4) void kconvt(
    const ushort* __restrict__ rp, const ushort* __restrict__ w2h,
    const float* __restrict__ img, ushort* __restrict__ rsh)
{
    const int tid = threadIdx.x;
    __shared__ uint4 lds[4096];   // 4 bufs x {A[512],B[512]} = 64 KB
    const int bx = blockIdx.x;
    const int bid = ((bx & 7) << 6) | (bx >> 3);   // XCD swizzle, 512%8==0
    const int m0 = bid * 64;
    const int lane = tid & 63, w = tid >> 6;
    const int q = w & 3, h = w >> 2;          // quadrant, K-half
    const int wm = q >> 1, wn = q & 1, g = lane >> 5;
    const int u = (lane & 7) ^ ((lane >> 3) & 7);   // pre-swizzled source unit

    // ---- T14 early prefetch of the epilogue img slab (consumed at end) ----
    const int b0 = m0 >> 8;
    const int x0 = ((m0 & 255) >> 4) * 8;
    const int erow = tid >> 4, ec0 = (tid & 15) * 8;
    const int ebase = b0 * DIM * DIM + (x0 + erow) * DIM + ec0;
    float4 im0 = *(const float4*)&img[ebase];
    float4 im1 = *(const float4*)&img[ebase + 4];
    __builtin_amdgcn_sched_barrier(0);   // pin: issued before staging

    // 16 slots: s<8 A-plane rows, s>=8 B-plane rows; wave w owns s=w*2..+1
    int off0[2]; const ushort* srcp[2];
#pragma unroll
    for (int i = 0; i < 2; ++i) {
        int s = w * 2 + i;
        if (s < 8) {
            int ml = s * 8 + (lane >> 3);
            int mm = m0 + ml;
            int b_ = mm >> 8, cell = mm & 255, px0 = cell >> 4, py0 = cell & 15;
            off0[i] = ((b_ * CP + px0 + 1) * CP + py0 + 1) * NAT + u * 8;
            srcp[i] = rp;
        } else {
            int ml = (s - 8) * 8 + (lane >> 3);
            off0[i] = ml * 512 + u * 8;
            srcp[i] = w2h;
        }
    }
    auto stage = [&](int kc, int buf) {
        int ij = kc >> 1;
        int dA = (kc & 1) * 64 - ((ij >> 1) * CP + (ij & 1)) * NAT;
        int dB = kc * 64;
        uint4* base = lds + buf * 1024;
#pragma unroll
        for (int i = 0; i < 2; ++i) {
            int s = w * 2 + i;
            GLOAD16(srcp[i] + off0[i] + (s < 8 ? dA : dB), base + s * 64);
        }
    };

    f32x16 acc = {};
    const int arow = wm * 32 + (lane & 31);
    const int brow = wn * 32 + (lane & 31);
    const int ax = lane & 7;     // = arow&7 = brow&7

    stage(0, 0); stage(1, 1); stage(2, 2); stage(3, 3);
    for (int s4 = 0; s4 < 4; ++s4) {
        if (s4 == 1)      { stage(4, 0); stage(5, 1); }   // buf0/1 freed by step0
        else if (s4 == 2) { stage(6, 2); stage(7, 3); }   // buf2/3 freed by step1
        if (s4 < 3) asm volatile("s_waitcnt vmcnt(4)" ::: "memory");
        else        asm volatile("s_waitcnt vmcnt(0)" ::: "memory");
        __builtin_amdgcn_s_barrier();            // pair (2s,2s+1) resident
        __builtin_amdgcn_sched_barrier(0);
        const uint4* Lb = lds + ((2 * s4 + h) & 3) * 1024;  // my K-half's chunk
#pragma unroll
        for (int ks = 0; ks < 4; ++ks) {
            int un = (ks * 2 + g) ^ ax;
            bf16x8 Ah = __builtin_bit_cast(bf16x8, Lb[      arow * 8 + un]);
            bf16x8 Bh = __builtin_bit_cast(bf16x8, Lb[512 + brow * 8 + un]);
            acc = __builtin_amdgcn_mfma_f32_32x32x16_bf16(Ah, Bh, acc, 0, 0, 0);
        }
        __builtin_amdgcn_sched_barrier(0);
        __builtin_amdgcn_s_barrier();            // all reads of this pair done
    }

    // ---- K-half reduce: h=0 writes xch (bufs0/1 region), h=1 adds ----
    float* xch  = (float*)lds;                    // 16 KB @ offset 0
    float* ldsO = (float*)lds + 8192;             // 16.5 KB @ offset 32 KB
    if (h == 0) {
#pragma unroll
        for (int f = 0; f < 16; ++f)
            xch[f * 256 + q * 64 + lane] = acc[f];
    }
    __syncthreads();
    if (h == 1) {
#pragma unroll
        for (int f = 0; f < 16; ++f)
            acc[f] += xch[f * 256 + q * 64 + lane];
        // stage 32x128 slab into ldsO (quadrant q)
        const int uvx = wn * 32 + (lane & 31);
        const int uu = uvx >> 3, vv = uvx & 7;
#pragma unroll
        for (int r = 0; r < 16; ++r) {
            int mr = m0 + wm * 32 + (r & 3) + 8 * (r >> 2) + 4 * g;
            int cl = mr & 255;
            ldsO[(((cl >> 4) & 3) * 8 + uu) * 129 + (cl & 15) * 8 + vv] = acc[r];
        }
    }
    __syncthreads();
    // ---- all 512 threads: coalesced resid write (1 uint4 each) ----
    const float* lrow = &ldsO[erow * 129 + ec0];
    uint hw[4];
    hw[0] = pk(f2bf(im0.x - lrow[0]), f2bf(im0.y - lrow[1]));
    hw[1] = pk(f2bf(im0.z - lrow[2]), f2bf(im0.w - lrow[3]));
    hw[2] = pk(f2bf(im1.x - lrow[4]), f2bf(im1.y - lrow[5]));
    hw[3] = pk(f2bf(im1.z - lrow[6]), f2bf(im1.w - lrow[7]));
    *(uint4*)&rsh[ebase] = uint4{hw[0], hw[1], hw[2], hw[3]};
}

// grad: pure-bf16 GEMM g[m=64 cells, n=64 atoms] = resid[m,256] x Wthi^T.
// Gate folded in (round-14): early partial-loads, tail decision gates writes.
__global__ __launch_bounds__(256) void kgrad(
    const ushort* __restrict__ rsh, const ushort* __restrict__ wth,
    ushort* __restrict__ rp, float* __restrict__ partials, int t)
{
    __shared__ uint4 lds[3072];   // 3 bufs x {A[512],B[512]} = 48 KB
    __shared__ float red0[16];
    __shared__ int sg;
    const int tid = threadIdx.x;
    const int bx = blockIdx.x;
    const int xcd = bx & 7;   // bijective XCD swizzle for nwg=450 (q=56,r=2)
    const int bid = (xcd < 2 ? xcd * 57 : 114 + (xcd - 2) * 56) + (bx >> 3);
    const int m0 = bid * 64;
    const int n0 = blockIdx.y * 64;
    const int lane = tid & 63, w = tid >> 6;
    const int wm = w >> 1, wn = w & 1, g = lane >> 5;
    const int u = (lane & 7) ^ ((lane >> 3) & 7);
    const int pb2 = blockIdx.y * 450 + bid;
    const float* bankO = partials + ((t - 1) & 1) * 2048;
    float* bankN = partials + (t & 1) * 2048;

    // ---- early loads: gate partials (t>=1) + own-slot copy + R state ----
    float gd[4] = {0.f, 0.f, 0.f, 0.f}, gr[4] = {0.f, 0.f, 0.f, 0.f};
    float pod = 0.f, por = 0.f;
    if (t >= 1) {
#pragma unroll
        for (int k = 0; k < 4; ++k) {
            int i = tid + k * 256;
            if (i < NGRAD) { gd[k] = bankO[i]; gr[k] = bankO[1024 + i]; }
        }
        pod = bankO[pb2]; por = bankO[1024 + pb2];
    }
    int rbase0, rbase1; uint4 rv0, rv1;
    {
        int item = tid;
        int rowL = item >> 3, ch = item & 7;
        int mr = m0 + rowL;
        int bb = mr / 225, rm = mr % 225, pxx = rm / 15, pyy = rm % 15;
        rbase0 = ((bb * CP + pxx + 1) * CP + pyy + 1) * NAT + n0 + ch * 8;
        rv0 = *(const uint4*)&rp[rbase0];
    }
    {
        int item = 256 + tid;
        int rowL = item >> 3, ch = item & 7;
        int mr = m0 + rowL;
        int bb = mr / 225, rm = mr % 225, pxx = rm / 15, pyy = rm % 15;
        rbase1 = ((bb * CP + pxx + 1) * CP + pyy + 1) * NAT + n0 + ch * 8;
        rv1 = *(const uint4*)&rp[rbase1];
    }
    __builtin_amdgcn_sched_barrier(0);   // pin: all early loads precede staging

    int off0[4]; const ushort* srcp[4];
#pragma unroll
    for (int i = 0; i < 4; ++i) {
        int s = w * 4 + i;
        if (s < 8) {
            int ml = s * 8 + (lane >> 3);
            int mA = m0 + ml, bA = mA / 225, rm = mA % 225, px = rm / 15, py = rm % 15;
            off0[i] = bA * DIM * DIM + (8 * px + (u >> 1)) * DIM + 8 * py + (u & 1) * 8;
            srcp[i] = rsh;
        } else {
            int ml = (s - 8) * 8 + (lane >> 3);
            off0[i] = (n0 + ml) * 256 + u * 8;
            srcp[i] = wth;
        }
    }
    auto stage = [&](int kc, int buf) {
        uint4* base = lds + buf * 1024;
#pragma unroll
        for (int i = 0; i < 4; ++i) {
            int s = w * 4 + i;
            GLOAD16(srcp[i] + off0[i] + (s < 8 ? kc * 512 : kc * 64), base + s * 64);
        }
    };

    f32x16 acc = {};
    const int arow = wm * 32 + (lane & 31);
    const int brow = wn * 32 + (lane & 31);
    const int ax = lane & 7;

    stage(0, 0); stage(1, 1);
    for (int kc = 0; kc < 4; ++kc) {
        if (kc < 2) stage(kc + 2, (kc + 2) % 3);
        int nf = 3 - kc; nf = nf > 2 ? 2 : nf;
        switch (nf) {
            case 2: asm volatile("s_waitcnt vmcnt(8)" ::: "memory"); break;
            case 1: asm volatile("s_waitcnt vmcnt(4)" ::: "memory"); break;
            default: asm volatile("s_waitcnt vmcnt(0)" ::: "memory"); break;
        }
        __builtin_amdgcn_s_barrier();
        __builtin_amdgcn_sched_barrier(0);
        const uint4* Lb = lds + (kc % 3) * 1024;
#pragma unroll
        for (int ks = 0; ks < 4; ++ks) {
            int un = (ks * 2 + g) ^ ax;
            bf16x8 Ah = __builtin_bit_cast(bf16x8, Lb[      arow * 8 + un]);
            bf16x8 Bh = __builtin_bit_cast(bf16x8, Lb[512 + brow * 8 + un]);
            acc = __builtin_amdgcn_mfma_f32_32x32x16_bf16(Ah, Bh, acc, 0, 0, 0);
        }
        __builtin_amdgcn_sched_barrier(0);
        __builtin_amdgcn_s_barrier();
    }

    // ---- finish gate decision (bit-identical order to old kconvt gate) ----
    int gate = 0;
    if (t >= 1) {
        float d2 = 0.f, r2 = 0.f;
        d2 += gd[0]; d2 += gd[1]; d2 += gd[2]; d2 += gd[3];
        r2 += gr[0]; r2 += gr[1]; r2 += gr[2]; r2 += gr[3];
        for (int off = 32; off; off >>= 1) { d2 += __shfl_down(d2, off, 64); r2 += __shfl_down(r2, off, 64); }
        int w_ = tid >> 6, l = tid & 63;
        if (l == 0) { red0[w_] = d2; red0[8 + w_] = r2; }
        __syncthreads();
        if (tid == 0) {
            float td = red0[0] + red0[1] + red0[2] + red0[3];
            float tr = red0[8] + red0[9] + red0[10] + red0[11];
            sg = (td < 1e-4f * tr) ? 1 : 0;
        }
        __syncthreads();
        gate = sg;
    }
    const bool dow = (t == 0) || (gate == 0);

    // ---- stage acc -> ldsO[64][76] (<=2-way conflicts both phases)
    float* ldsO = (float*)lds;
    {
        const int colL = wn * 32 + (lane & 31);
#pragma unroll
        for (int r = 0; r < 16; ++r) {
            int rowL = wm * 32 + (r & 3) + 8 * (r >> 2) + 4 * g;
            ldsO[rowL * 76 + colL] = acc[r];
        }
    }
    __syncthreads();

    // ---- RMW on prefetched R: 2 items/thread, 8 atoms each (gated)
    float d2 = 0.f, r2 = 0.f;
    if (dow) {
#pragma unroll
        for (int i = 0; i < 2; ++i) {
            int item = i * 256 + tid;
            int rowL = item >> 3, ch = item & 7;
            uint4 hv = i ? rv1 : rv0;
            int base = i ? rbase1 : rbase0;
            const float* lp = &ldsO[rowL * 76 + ch * 8];
            uint ho[4];
#pragma unroll
            for (int wd = 0; wd < 4; ++wd) {
                uint hw_ = ((const uint*)&hv)[wd];
                ushort nh0, nh1;
                {
                    float rold = us2f((ushort)hw_);
                    float v = fmaf(STEP, lp[wd * 2 + 0], rold);
                    float st = fmaxf(v - LMD, 0.f) - fmaxf(-v - LMD, 0.f);
                    nh0 = f2bf(st);
                    float df = us2f(nh0) - rold;      // stored-state delta
                    d2 += df * df; r2 += rold * rold;
                }
                {
                    float rold = us2f((ushort)(hw_ >> 16));
                    float v = fmaf(STEP, lp[wd * 2 + 1], rold);
                    float st = fmaxf(v - LMD, 0.f) - fmaxf(-v - LMD, 0.f);
                    nh1 = f2bf(st);
                    float df = us2f(nh1) - rold;
                    d2 += df * df; r2 += rold * rold;
                }
                ho[wd] = pk(nh0, nh1);
            }
            *(uint4*)&rp[base] = uint4{ho[0], ho[1], ho[2], ho[3]};
        }
    }

    for (int off = 32; off; off >>= 1) { d2 += __shfl_down(d2, off, 64); r2 += __shfl_down(r2, off, 64); }
    int w_ = tid >> 6, l = tid & 63;
    if (l == 0) { red0[w_] = d2; red0[8 + w_] = r2; }
    __syncthreads();
    if (tid == 0) {
        if (dow) {
            float td = red0[0] + red0[1] + red0[2] + red0[3];
            float tr = red0[8] + red0[9] + red0[10] + red0[11];
            bankN[pb2] = td;
            bankN[1024 + pb2] = tr;
        } else {   // converged: freeze partials (copy own slot forward)
            bankN[pb2] = pod;
            bankN[1024 + pb2] = por;
        }
    }
}

// final reconstruction: C = R x (W2hi + W2lo)^T, fp32 out.
__global__ __launch_bounds__(256) void kfinal(
    const ushort* __restrict__ rp,
    const ushort* __restrict__ w2h, const ushort* __restrict__ w2l,
    float* __restrict__ outp)
{
    const int tid = threadIdx.x;
    __shared__ uint4 lds[3072];   // 2 bufs x {A[512],Bh[512],Bl[512]} = 48 KB
    const int bx = blockIdx.x;
    const int bid = ((bx & 7) << 6) | (bx >> 3);
    const int m0 = bid * 64;
    const int lane = tid & 63, w = tid >> 6;
    const int wm = w >> 1, wn = w & 1, g = lane >> 5;
    const int u = (lane & 7) ^ ((lane >> 3) & 7);

    // 24 slots: 0-7 A rows, 8-15 Bh rows, 16-23 Bl rows; wave w owns w*6..+5
    const ushort* const srcs[3] = {rp, w2h, w2l};
    int off0[6]; const ushort* srcp[6];
#pragma unroll
    for (int i = 0; i < 6; ++i) {
        int j = w * 6 + i, p = j >> 3, jj = j & 7;
        int ml = jj * 8 + (lane >> 3);
        srcp[i] = srcs[p];
        if (p == 0) {
            int mm = m0 + ml;
            int b_ = mm >> 8, cell = mm & 255, px0 = cell >> 4, py0 = cell & 15;
            off0[i] = ((b_ * CP + px0 + 1) * CP + py0 + 1) * NAT + u * 8;
        } else {
            off0[i] = ml * 512 + u * 8;
        }
    }
    auto stage = [&](int kc, int buf) {
        int ij = kc >> 1;
        int dA = (kc & 1) * 64 - ((ij >> 1) * CP + (ij & 1)) * NAT;
        int dB = kc * 64;
#pragma unroll
        for (int i = 0; i < 6; ++i) {
            int j = w * 6 + i;
            GLOAD16(srcp[i] + off0[i] + (j < 8 ? dA : dB), lds + buf * 1536 + j * 64);
        }
    };

    f32x16 acc = {};
    const int arow = wm * 32 + (lane & 31);
    const int brow = wn * 32 + (lane & 31);
    const int ax = lane & 7;

    stage(0, 0);
    __syncthreads();
    for (int kc = 0;; ++kc) {
        const int cur = kc & 1;
        if (kc < 7) stage(kc + 1, cur ^ 1);
        const uint4* Lb = lds + cur * 1536;
#pragma unroll
        for (int ks = 0; ks < 4; ++ks) {
            int un = (ks * 2 + g) ^ ax;
            bf16x8 Ah = __builtin_bit_cast(bf16x8, Lb[       arow * 8 + un]);
            bf16x8 Bh = __builtin_bit_cast(bf16x8, Lb[512  + brow * 8 + un]);
            bf16x8 Bl = __builtin_bit_cast(bf16x8, Lb[1024 + brow * 8 + un]);
            acc = __builtin_amdgcn_mfma_f32_32x32x16_bf16(Ah, Bh, acc, 0, 0, 0);
            acc = __builtin_amdgcn_mfma_f32_32x32x16_bf16(Ah, Bl, acc, 0, 0, 0);
        }
        if (kc == 7) break;
        __syncthreads();
    }

    __syncthreads();
    float* ldsO = (float*)lds;
    const int uvx = wn * 32 + (lane & 31);
    const int uu = uvx >> 3, vv = uvx & 7;
#pragma unroll
    for (int r = 0; r < 16; ++r) {
        int mr = m0 + wm * 32 + (r & 3) + 8 * (r >> 2) + 4 * g;
        int cl = mr & 255;
        ldsO[(((cl >> 4) & 3) * 8 + uu) * 129 + (cl & 15) * 8 + vv] = acc[r];
    }
    __syncthreads();
    const int b0 = m0 >> 8;
    const int x0 = ((m0 & 255) >> 4) * 8;
    const int row = tid >> 3, c0 = (tid & 7) * 16;
    const int base = b0 * DIM * DIM + (x0 + row) * DIM + c0;
    const float* lrow = &ldsO[row * 129 + c0];
#pragma unroll
    for (int v = 0; v < 4; ++v)
        *(float4*)&outp[base + v * 4] =
            float4{lrow[v*4], lrow[v*4+1], lrow[v*4+2], lrow[v*4+3]};
}

extern "C" void kernel_launch(void* const* d_in, const int* in_sizes, int n_in,
                              void* d_out, int out_size, void* d_ws, size_t ws_size,
                              hipStream_t stream) {
    const float* img = (const float*)d_in[0];
    const float* W   = (const float*)d_in[1];
    char* ws = (char*)d_ws;
    ushort* rp  = (ushort*)(ws + O_RP);
    ushort* rsh = (ushort*)(ws + O_RSH);
    ushort* w2h = (ushort*)(ws + O_W2H);
    ushort* w2l = (ushort*)(ws + O_W2L);
    ushort* wth = (ushort*)(ws + O_WTH);
    ushort* wtl = (ushort*)(ws + O_WTL);
    float* partials = (float*)(ws + O_PART);
    float* outp = (float*)d_out;

    kzero<<<2312, 256, 0, stream>>>((uint4*)(ws + O_RP));   // R plane = 9.47 MB
    kprep<<<128, 256, 0, stream>>>(W, wth, wtl, w2h, w2l);
    kinit0<<<1024, 256, 0, stream>>>(img, rsh);             // t=0: resid = img
    kgrad<<<dim3(450, 2), 256, 0, stream>>>(rsh, wth, rp, partials, 0);
    for (int t = 1; t < MAXIT; ++t) {
        kconvt<<<512, 512, 0, stream>>>(rp, w2h, img, rsh);
        kgrad<<<dim3(450, 2), 256, 0, stream>>>(rsh, wth, rp, partials, t);
    }
    kfinal<<<512, 256, 0, stream>>>(rp, w2h, w2l, outp);
}

// Round 16
// 425.297 us; speedup vs baseline: 1.0167x; 1.0167x over previous
//
#include <hip/hip_runtime.h>
#include <stdint.h>

#define BATCH 128
#define NAT   128
#define DIM   128
#define CP    17
#define MAXIT 20
#define STEP  0.2f      // 2 * R_LR
#define LMD   0.005f
#define NGRAD 900

typedef short bf16x8 __attribute__((ext_vector_type(8)));   // 8 bf16 (4 VGPR)
typedef float f32x16 __attribute__((ext_vector_type(16)));  // 32x32 C/D

#define SZ_RP (BATCH*CP*CP*NAT)     // 4,734,976 elems
#define SZ_RS (BATCH*DIM*DIM)       // 2,097,152 elems
// workspace byte offsets (all 16B-aligned). R = single bf16 plane.
#define O_RP   0
#define O_RSH  (O_RP + SZ_RP*2)
#define O_W2H  (O_RSH + SZ_RS*2)
#define O_W2L  (O_W2H + 64*512*2)
#define O_WTH  (O_W2L + 64*512*2)
#define O_WTL  (O_WTH + 128*256*2)
#define O_PART (O_WTL + 128*256*2)   // 2 banks x 2048 floats (parity dbuf)
#define O_IMB  (O_PART + 4096*4)     // img as bf16 plane (4.2 MB)

#define GLOAD16(gp, lp) __builtin_amdgcn_global_load_lds( \
    (const __attribute__((address_space(1))) uint32_t*)(gp), \
    (__attribute__((address_space(3))) uint32_t*)(lp), 16, 0, 0)

// split fp32 -> hi/lo bf16 (RNE)
__device__ __forceinline__ void split2(float x, ushort& h, ushort& l) {
    uint32_t u = __float_as_uint(x);
    uint32_t hr = (u + 0x7FFFu + ((u >> 16) & 1u)) >> 16;
    h = (ushort)hr;
    float r = x - __uint_as_float(hr << 16);
    uint32_t u2 = __float_as_uint(r);
    l = (ushort)((u2 + 0x7FFFu + ((u2 >> 16) & 1u)) >> 16);
}
__device__ __forceinline__ float us2f(ushort u) {
    return __uint_as_float(((uint32_t)u) << 16);
}
__device__ __forceinline__ uint pk(ushort a, ushort b) {
    return (uint)a | ((uint)b << 16);
}
__device__ __forceinline__ ushort f2bf(float x) {   // RNE round to bf16
    uint32_t u = __float_as_uint(x);
    return (ushort)((u + 0x7FFFu + ((u >> 16) & 1u)) >> 16);
}

__global__ void kzero(uint4* __restrict__ rp) {
    int i = blockIdx.x * 256 + threadIdx.x;
    rp[i] = uint4{0u, 0u, 0u, 0u};   // R single plane
}

// WtT = W layout [n][256]; W2T[uv][ij*128+n]; both as hi/lo bf16 planes
__global__ void kprep(const float* __restrict__ W,
                      ushort* __restrict__ wth, ushort* __restrict__ wtl,
                      ushort* __restrict__ w2h, ushort* __restrict__ w2l) {
    int tid = blockIdx.x * 256 + threadIdx.x;   // 32768
    int n = tid >> 8, kk = tid & 255;
    ushort h, l; split2(W[tid], h, l);
    wth[tid] = h; wtl[tid] = l;
    int kx = kk >> 4, ky = kk & 15;
    int uv = (kx & 7) * 8 + (ky & 7);
    int k2 = ((kx >> 3) * 2 + (ky >> 3)) * 128 + n;
    w2h[uv * 512 + k2] = h; w2l[uv * 512 + k2] = l;
}

// t=0: resid = img (bf16) AND persistent img-bf16 plane for kconvt's epilogue
__global__ void kinit0(const float* __restrict__ img, ushort* __restrict__ rsh,
                       ushort* __restrict__ imb) {
    int t8 = (blockIdx.x * 256 + threadIdx.x) * 8;
    uint hw[4];
#pragma unroll
    for (int v = 0; v < 2; ++v) {
        float4 im = *(const float4*)&img[t8 + v * 4];
        hw[v*2+0] = pk(f2bf(im.x), f2bf(im.y));
        hw[v*2+1] = pk(f2bf(im.z), f2bf(im.w));
    }
    uint4 pkd{hw[0], hw[1], hw[2], hw[3]};
    *(uint4*)&rsh[t8] = pkd;
    *(uint4*)&imb[t8] = pkd;
}

// resid kconvt: pure-bf16 GEMM C[m=cell,uv] = R[m,512] x W2hi^T. UNGATED
// (idempotent when converged). Depth-3 prefetch, 4 LDS bufs, counted vmcnt.
// Epilogue subtracts from the bf16 img plane (half the fetch of fp32 img).
__global__ __launch_bounds__(256) void kconvt(
    const ushort* __restrict__ rp, const ushort* __restrict__ w2h,
    const ushort* __restrict__ imb, ushort* __restrict__ rsh)
{
    const int tid = threadIdx.x;
    __shared__ uint4 lds[4096];   // 4 bufs x {A[512],B[512]} = 64 KB
    const int bx = blockIdx.x;
    const int bid = ((bx & 7) << 6) | (bx >> 3);   // XCD swizzle, 512%8==0
    const int m0 = bid * 64;
    const int lane = tid & 63, w = tid >> 6;
    const int wm = w >> 1, wn = w & 1, g = lane >> 5;
    const int u = (lane & 7) ^ ((lane >> 3) & 7);   // pre-swizzled source unit

    // ---- T14 early prefetch of the epilogue img slab (bf16, 2 uint4) ----
    const int b0 = m0 >> 8;
    const int x0 = ((m0 & 255) >> 4) * 8;
    const int erow = tid >> 3, ec0 = (tid & 7) * 16;
    const int ebase = b0 * DIM * DIM + (x0 + erow) * DIM + ec0;
    uint4 ib0 = *(const uint4*)&imb[ebase];
    uint4 ib1 = *(const uint4*)&imb[ebase + 8];
    __builtin_amdgcn_sched_barrier(0);   // pin: issued before staging

    // 16 slots: s<8 A-plane rows, s>=8 B-plane rows; wave w owns s=w*4..+3
    int off0[4]; const ushort* srcp[4];
#pragma unroll
    for (int i = 0; i < 4; ++i) {
        int s = w * 4 + i;
        if (s < 8) {
            int ml = s * 8 + (lane >> 3);
            int mm = m0 + ml;
            int b_ = mm >> 8, cell = mm & 255, px0 = cell >> 4, py0 = cell & 15;
            off0[i] = ((b_ * CP + px0 + 1) * CP + py0 + 1) * NAT + u * 8;
            srcp[i] = rp;
        } else {
            int ml = (s - 8) * 8 + (lane >> 3);
            off0[i] = ml * 512 + u * 8;
            srcp[i] = w2h;
        }
    }
    auto stage = [&](int kc, int buf) {
        int ij = kc >> 1;
        int dA = (kc & 1) * 64 - ((ij >> 1) * CP + (ij & 1)) * NAT;
        int dB = kc * 64;
        uint4* base = lds + buf * 1024;
#pragma unroll
        for (int i = 0; i < 4; ++i) {
            int s = w * 4 + i;
            GLOAD16(srcp[i] + off0[i] + (s < 8 ? dA : dB), base + s * 64);
        }
    };

    f32x16 acc = {};
    const int arow = wm * 32 + (lane & 31);
    const int brow = wn * 32 + (lane & 31);
    const int ax = lane & 7;     // = arow&7 = brow&7

    stage(0, 0); stage(1, 1); stage(2, 2);
    for (int kc = 0; kc < 8; ++kc) {
        if (kc < 5) stage(kc + 3, (kc + 3) & 3);
        int nf = 7 - kc; nf = nf > 3 ? 3 : nf;    // chunks in flight past kc
        switch (nf) {
            case 3: asm volatile("s_waitcnt vmcnt(12)" ::: "memory"); break;
            case 2: asm volatile("s_waitcnt vmcnt(8)"  ::: "memory"); break;
            case 1: asm volatile("s_waitcnt vmcnt(4)"  ::: "memory"); break;
            default: asm volatile("s_waitcnt vmcnt(0)" ::: "memory"); break;
        }
        __builtin_amdgcn_s_barrier();            // chunk kc resident for all waves
        __builtin_amdgcn_sched_barrier(0);
        const uint4* Lb = lds + (kc & 3) * 1024;
#pragma unroll
        for (int ks = 0; ks < 4; ++ks) {
            int un = (ks * 2 + g) ^ ax;
            bf16x8 Ah = __builtin_bit_cast(bf16x8, Lb[      arow * 8 + un]);
            bf16x8 Bh = __builtin_bit_cast(bf16x8, Lb[512 + brow * 8 + un]);
            acc = __builtin_amdgcn_mfma_f32_32x32x16_bf16(Ah, Bh, acc, 0, 0, 0);
        }
        __builtin_amdgcn_sched_barrier(0);
        __builtin_amdgcn_s_barrier();            // buf free for overwrite
    }

    // ---- epilogue: stage 32x128 slab in LDS, write resid coalesced ----
    float* ldsO = (float*)lds;            // [32][129] fp32
    const int uvx = wn * 32 + (lane & 31);
    const int uu = uvx >> 3, vv = uvx & 7;
#pragma unroll
    for (int r = 0; r < 16; ++r) {
        int mr = m0 + wm * 32 + (r & 3) + 8 * (r >> 2) + 4 * g;
        int cl = mr & 255;
        ldsO[(((cl >> 4) & 3) * 8 + uu) * 129 + (cl & 15) * 8 + vv] = acc[r];
    }
    __syncthreads();
    const float* lrow = &ldsO[erow * 129 + ec0];
    const uint* iw0 = (const uint*)&ib0;
    const uint* iw1 = (const uint*)&ib1;
    uint hw[8];
#pragma unroll
    for (int w4 = 0; w4 < 4; ++w4) {
        hw[w4] = pk(f2bf(us2f((ushort)iw0[w4])         - lrow[2 * w4 + 0]),
                    f2bf(us2f((ushort)(iw0[w4] >> 16)) - lrow[2 * w4 + 1]));
        hw[4 + w4] = pk(f2bf(us2f((ushort)iw1[w4])         - lrow[8 + 2 * w4 + 0]),
                        f2bf(us2f((ushort)(iw1[w4] >> 16)) - lrow[8 + 2 * w4 + 1]));
    }
    *(uint4*)&rsh[ebase]     = uint4{hw[0],hw[1],hw[2],hw[3]};
    *(uint4*)&rsh[ebase + 8] = uint4{hw[4],hw[5],hw[6],hw[7]};
}

// grad: pure-bf16 GEMM g[m=64 cells, n=64 atoms] = resid[m,256] x Wthi^T.
// Gate folded in (round-14): early partial-loads, tail decision gates writes.
__global__ __launch_bounds__(256) void kgrad(
    const ushort* __restrict__ rsh, const ushort* __restrict__ wth,
    ushort* __restrict__ rp, float* __restrict__ partials, int t)
{
    __shared__ uint4 lds[3072];   // 3 bufs x {A[512],B[512]} = 48 KB
    __shared__ float red0[16];
    __shared__ int sg;
    const int tid = threadIdx.x;
    const int bx = blockIdx.x;
    const int xcd = bx & 7;   // bijective XCD swizzle for nwg=450 (q=56,r=2)
    const int bid = (xcd < 2 ? xcd * 57 : 114 + (xcd - 2) * 56) + (bx >> 3);
    const int m0 = bid * 64;
    const int n0 = blockIdx.y * 64;
    const int lane = tid & 63, w = tid >> 6;
    const int wm = w >> 1, wn = w & 1, g = lane >> 5;
    const int u = (lane & 7) ^ ((lane >> 3) & 7);
    const int pb2 = blockIdx.y * 450 + bid;
    const float* bankO = partials + ((t - 1) & 1) * 2048;
    float* bankN = partials + (t & 1) * 2048;

    // ---- early loads: gate partials (t>=1) + own-slot copy + R state ----
    float gd[4] = {0.f, 0.f, 0.f, 0.f}, gr[4] = {0.f, 0.f, 0.f, 0.f};
    float pod = 0.f, por = 0.f;
    if (t >= 1) {
#pragma unroll
        for (int k = 0; k < 4; ++k) {
            int i = tid + k * 256;
            if (i < NGRAD) { gd[k] = bankO[i]; gr[k] = bankO[1024 + i]; }
        }
        pod = bankO[pb2]; por = bankO[1024 + pb2];
    }
    int rbase0, rbase1; uint4 rv0, rv1;
    {
        int item = tid;
        int rowL = item >> 3, ch = item & 7;
        int mr = m0 + rowL;
        int bb = mr / 225, rm = mr % 225, pxx = rm / 15, pyy = rm % 15;
        rbase0 = ((bb * CP + pxx + 1) * CP + pyy + 1) * NAT + n0 + ch * 8;
        rv0 = *(const uint4*)&rp[rbase0];
    }
    {
        int item = 256 + tid;
        int rowL = item >> 3, ch = item & 7;
        int mr = m0 + rowL;
        int bb = mr / 225, rm = mr % 225, pxx = rm / 15, pyy = rm % 15;
        rbase1 = ((bb * CP + pxx + 1) * CP + pyy + 1) * NAT + n0 + ch * 8;
        rv1 = *(const uint4*)&rp[rbase1];
    }
    __builtin_amdgcn_sched_barrier(0);   // pin: all early loads precede staging

    int off0[4]; const ushort* srcp[4];
#pragma unroll
    for (int i = 0; i < 4; ++i) {
        int s = w * 4 + i;
        if (s < 8) {
            int ml = s * 8 + (lane >> 3);
            int mA = m0 + ml, bA = mA / 225, rm = mA % 225, px = rm / 15, py = rm % 15;
            off0[i] = bA * DIM * DIM + (8 * px + (u >> 1)) * DIM + 8 * py + (u & 1) * 8;
            srcp[i] = rsh;
        } else {
            int ml = (s - 8) * 8 + (lane >> 3);
            off0[i] = (n0 + ml) * 256 + u * 8;
            srcp[i] = wth;
        }
    }
    auto stage = [&](int kc, int buf) {
        uint4* base = lds + buf * 1024;
#pragma unroll
        for (int i = 0; i < 4; ++i) {
            int s = w * 4 + i;
            GLOAD16(srcp[i] + off0[i] + (s < 8 ? kc * 512 : kc * 64), base + s * 64);
        }
    };

    f32x16 acc = {};
    const int arow = wm * 32 + (lane & 31);
    const int brow = wn * 32 + (lane & 31);
    const int ax = lane & 7;

    stage(0, 0); stage(1, 1);
    for (int kc = 0; kc < 4; ++kc) {
        if (kc < 2) stage(kc + 2, (kc + 2) % 3);
        int nf = 3 - kc; nf = nf > 2 ? 2 : nf;
        switch (nf) {
            case 2: asm volatile("s_waitcnt vmcnt(8)" ::: "memory"); break;
            case 1: asm volatile("s_waitcnt vmcnt(4)" ::: "memory"); break;
            default: asm volatile("s_waitcnt vmcnt(0)" ::: "memory"); break;
        }
        __builtin_amdgcn_s_barrier();
        __builtin_amdgcn_sched_barrier(0);
        const uint4* Lb = lds + (kc % 3) * 1024;
#pragma unroll
        for (int ks = 0; ks < 4; ++ks) {
            int un = (ks * 2 + g) ^ ax;
            bf16x8 Ah = __builtin_bit_cast(bf16x8, Lb[      arow * 8 + un]);
            bf16x8 Bh = __builtin_bit_cast(bf16x8, Lb[512 + brow * 8 + un]);
            acc = __builtin_amdgcn_mfma_f32_32x32x16_bf16(Ah, Bh, acc, 0, 0, 0);
        }
        __builtin_amdgcn_sched_barrier(0);
        __builtin_amdgcn_s_barrier();
    }

    // ---- finish gate decision (bit-identical order to old kconvt gate) ----
    int gate = 0;
    if (t >= 1) {
        float d2 = 0.f, r2 = 0.f;
        d2 += gd[0]; d2 += gd[1]; d2 += gd[2]; d2 += gd[3];
        r2 += gr[0]; r2 += gr[1]; r2 += gr[2]; r2 += gr[3];
        for (int off = 32; off; off >>= 1) { d2 += __shfl_down(d2, off, 64); r2 += __shfl_down(r2, off, 64); }
        int w_ = tid >> 6, l = tid & 63;
        if (l == 0) { red0[w_] = d2; red0[8 + w_] = r2; }
        __syncthreads();
        if (tid == 0) {
            float td = red0[0] + red0[1] + red0[2] + red0[3];
            float tr = red0[8] + red0[9] + red0[10] + red0[11];
            sg = (td < 1e-4f * tr) ? 1 : 0;
        }
        __syncthreads();
        gate = sg;
    }
    const bool dow = (t == 0) || (gate == 0);

    // ---- stage acc -> ldsO[64][76] (<=2-way conflicts both phases)
    float* ldsO = (float*)lds;
    {
        const int colL = wn * 32 + (lane & 31);
#pragma unroll
        for (int r = 0; r < 16; ++r) {
            int rowL = wm * 32 + (r & 3) + 8 * (r >> 2) + 4 * g;
            ldsO[rowL * 76 + colL] = acc[r];
        }
    }
    __syncthreads();

    // ---- RMW on prefetched R: 2 items/thread, 8 atoms each (gated)
    float d2 = 0.f, r2 = 0.f;
    if (dow) {
#pragma unroll
        for (int i = 0; i < 2; ++i) {
            int item = i * 256 + tid;
            int rowL = item >> 3, ch = item & 7;
            uint4 hv = i ? rv1 : rv0;
            int base = i ? rbase1 : rbase0;
            const float* lp = &ldsO[rowL * 76 + ch * 8];
            uint ho[4];
#pragma unroll
            for (int wd = 0; wd < 4; ++wd) {
                uint hw_ = ((const uint*)&hv)[wd];
                ushort nh0, nh1;
                {
                    float rold = us2f((ushort)hw_);
                    float v = fmaf(STEP, lp[wd * 2 + 0], rold);
                    float st = fmaxf(v - LMD, 0.f) - fmaxf(-v - LMD, 0.f);
                    nh0 = f2bf(st);
                    float df = us2f(nh0) - rold;      // stored-state delta
                    d2 += df * df; r2 += rold * rold;
                }
                {
                    float rold = us2f((ushort)(hw_ >> 16));
                    float v = fmaf(STEP, lp[wd * 2 + 1], rold);
                    float st = fmaxf(v - LMD, 0.f) - fmaxf(-v - LMD, 0.f);
                    nh1 = f2bf(st);
                    float df = us2f(nh1) - rold;
                    d2 += df * df; r2 += rold * rold;
                }
                ho[wd] = pk(nh0, nh1);
            }
            *(uint4*)&rp[base] = uint4{ho[0], ho[1], ho[2], ho[3]};
        }
    }

    for (int off = 32; off; off >>= 1) { d2 += __shfl_down(d2, off, 64); r2 += __shfl_down(r2, off, 64); }
    int w_ = tid >> 6, l = tid & 63;
    if (l == 0) { red0[w_] = d2; red0[8 + w_] = r2; }
    __syncthreads();
    if (tid == 0) {
        if (dow) {
            float td = red0[0] + red0[1] + red0[2] + red0[3];
            float tr = red0[8] + red0[9] + red0[10] + red0[11];
            bankN[pb2] = td;
            bankN[1024 + pb2] = tr;
        } else {   // converged: freeze partials (copy own slot forward)
            bankN[pb2] = pod;
            bankN[1024 + pb2] = por;
        }
    }
}

// final reconstruction: C = R x (W2hi + W2lo)^T, fp32 out.
__global__ __launch_bounds__(256) void kfinal(
    const ushort* __restrict__ rp,
    const ushort* __restrict__ w2h, const ushort* __restrict__ w2l,
    float* __restrict__ outp)
{
    const int tid = threadIdx.x;
    __shared__ uint4 lds[3072];   // 2 bufs x {A[512],Bh[512],Bl[512]} = 48 KB
    const int bx = blockIdx.x;
    const int bid = ((bx & 7) << 6) | (bx >> 3);
    const int m0 = bid * 64;
    const int lane = tid & 63, w = tid >> 6;
    const int wm = w >> 1, wn = w & 1, g = lane >> 5;
    const int u = (lane & 7) ^ ((lane >> 3) & 7);

    // 24 slots: 0-7 A rows, 8-15 Bh rows, 16-23 Bl rows; wave w owns w*6..+5
    const ushort* const srcs[3] = {rp, w2h, w2l};
    int off0[6]; const ushort* srcp[6];
#pragma unroll
    for (int i = 0; i < 6; ++i) {
        int j = w * 6 + i, p = j >> 3, jj = j & 7;
        int ml = jj * 8 + (lane >> 3);
        srcp[i] = srcs[p];
        if (p == 0) {
            int mm = m0 + ml;
            int b_ = mm >> 8, cell = mm & 255, px0 = cell >> 4, py0 = cell & 15;
            off0[i] = ((b_ * CP + px0 + 1) * CP + py0 + 1) * NAT + u * 8;
        } else {
            off0[i] = ml * 512 + u * 8;
        }
    }
    auto stage = [&](int kc, int buf) {
        int ij = kc >> 1;
        int dA = (kc & 1) * 64 - ((ij >> 1) * CP + (ij & 1)) * NAT;
        int dB = kc * 64;
#pragma unroll
        for (int i = 0; i < 6; ++i) {
            int j = w * 6 + i;
            GLOAD16(srcp[i] + off0[i] + (j < 8 ? dA : dB), lds + buf * 1536 + j * 64);
        }
    };

    f32x16 acc = {};
    const int arow = wm * 32 + (lane & 31);
    const int brow = wn * 32 + (lane & 31);
    const int ax = lane & 7;

    stage(0, 0);
    __syncthreads();
    for (int kc = 0;; ++kc) {
        const int cur = kc & 1;
        if (kc < 7) stage(kc + 1, cur ^ 1);
        const uint4* Lb = lds + cur * 1536;
#pragma unroll
        for (int ks = 0; ks < 4; ++ks) {
            int un = (ks * 2 + g) ^ ax;
            bf16x8 Ah = __builtin_bit_cast(bf16x8, Lb[       arow * 8 + un]);
            bf16x8 Bh = __builtin_bit_cast(bf16x8, Lb[512  + brow * 8 + un]);
            bf16x8 Bl = __builtin_bit_cast(bf16x8, Lb[1024 + brow * 8 + un]);
            acc = __builtin_amdgcn_mfma_f32_32x32x16_bf16(Ah, Bh, acc, 0, 0, 0);
            acc = __builtin_amdgcn_mfma_f32_32x32x16_bf16(Ah, Bl, acc, 0, 0, 0);
        }
        if (kc == 7) break;
        __syncthreads();
    }

    __syncthreads();
    float* ldsO = (float*)lds;
    const int uvx = wn * 32 + (lane & 31);
    const int uu = uvx >> 3, vv = uvx & 7;
#pragma unroll
    for (int r = 0; r < 16; ++r) {
        int mr = m0 + wm * 32 + (r & 3) + 8 * (r >> 2) + 4 * g;
        int cl = mr & 255;
        ldsO[(((cl >> 4) & 3) * 8 + uu) * 129 + (cl & 15) * 8 + vv] = acc[r];
    }
    __syncthreads();
    const int b0 = m0 >> 8;
    const int x0 = ((m0 & 255) >> 4) * 8;
    const int row = tid >> 3, c0 = (tid & 7) * 16;
    const int base = b0 * DIM * DIM + (x0 + row) * DIM + c0;
    const float* lrow = &ldsO[row * 129 + c0];
#pragma unroll
    for (int v = 0; v < 4; ++v)
        *(float4*)&outp[base + v * 4] =
            float4{lrow[v*4], lrow[v*4+1], lrow[v*4+2], lrow[v*4+3]};
}

extern "C" void kernel_launch(void* const* d_in, const int* in_sizes, int n_in,
                              void* d_out, int out_size, void* d_ws, size_t ws_size,
                              hipStream_t stream) {
    const float* img = (const float*)d_in[0];
    const float* W   = (const float*)d_in[1];
    char* ws = (char*)d_ws;
    ushort* rp  = (ushort*)(ws + O_RP);
    ushort* rsh = (ushort*)(ws + O_RSH);
    ushort* w2h = (ushort*)(ws + O_W2H);
    ushort* w2l = (ushort*)(ws + O_W2L);
    ushort* wth = (ushort*)(ws + O_WTH);
    ushort* wtl = (ushort*)(ws + O_WTL);
    float* partials = (float*)(ws + O_PART);
    ushort* imb = (ushort*)(ws + O_IMB);
    float* outp = (float*)d_out;

    kzero<<<2312, 256, 0, stream>>>((uint4*)(ws + O_RP));   // R plane = 9.47 MB
    kprep<<<128, 256, 0, stream>>>(W, wth, wtl, w2h, w2l);
    kinit0<<<1024, 256, 0, stream>>>(img, rsh, imb);        // resid = img; imb = bf16(img)
    kgrad<<<dim3(450, 2), 256, 0, stream>>>(rsh, wth, rp, partials, 0);
    for (int t = 1; t < MAXIT; ++t) {
        kconvt<<<512, 256, 0, stream>>>(rp, w2h, imb, rsh);
        kgrad<<<dim3(450, 2), 256, 0, stream>>>(rsh, wth, rp, partials, t);
    }
    kfinal<<<512, 256, 0, stream>>>(rp, w2h, w2l, outp);
}

// Round 17
// 386.270 us; speedup vs baseline: 1.1194x; 1.1010x over previous
//
#include <hip/hip_runtime.h>
#include <stdint.h>

#define BATCH 128
#define NAT   128
#define DIM   128
#define CP    17
#define MAXIT 20
#define STEP  0.2f      // 2 * R_LR
#define LMD   0.005f
#define NGRAD 900

typedef short bf16x8 __attribute__((ext_vector_type(8)));   // 8 bf16 (4 VGPR)
typedef float f32x16 __attribute__((ext_vector_type(16)));  // 32x32 C/D

#define SZ_RP (BATCH*CP*CP*NAT)     // 4,734,976 elems
#define SZ_RS (BATCH*DIM*DIM)       // 2,097,152 elems
// workspace byte offsets (all 16B-aligned). R = single bf16 plane.
#define O_RP   0
#define O_RSH  (O_RP + SZ_RP*2)
#define O_W2H  (O_RSH + SZ_RS*2)
#define O_W2L  (O_W2H + 64*512*2)
#define O_WTH  (O_W2L + 64*512*2)
#define O_WTL  (O_WTH + 128*256*2)
#define O_PART (O_WTL + 128*256*2)   // 2 banks x 2048 floats (parity dbuf)
#define O_IMB  (O_PART + 4096*4)     // img as bf16 plane (4.2 MB)

#define GLOAD16(gp, lp) __builtin_amdgcn_global_load_lds( \
    (const __attribute__((address_space(1))) uint32_t*)(gp), \
    (__attribute__((address_space(3))) uint32_t*)(lp), 16, 0, 0)

// split fp32 -> hi/lo bf16 (RNE)
__device__ __forceinline__ void split2(float x, ushort& h, ushort& l) {
    uint32_t u = __float_as_uint(x);
    uint32_t hr = (u + 0x7FFFu + ((u >> 16) & 1u)) >> 16;
    h = (ushort)hr;
    float r = x - __uint_as_float(hr << 16);
    uint32_t u2 = __float_as_uint(r);
    l = (ushort)((u2 + 0x7FFFu + ((u2 >> 16) & 1u)) >> 16);
}
__device__ __forceinline__ float us2f(ushort u) {
    return __uint_as_float(((uint32_t)u) << 16);
}
__device__ __forceinline__ uint pk(ushort a, ushort b) {
    return (uint)a | ((uint)b << 16);
}
__device__ __forceinline__ ushort f2bf(float x) {   // RNE round to bf16
    uint32_t u = __float_as_uint(x);
    return (ushort)((u + 0x7FFFu + ((u >> 16) & 1u)) >> 16);
}

__global__ void kzero(uint4* __restrict__ rp) {
    int i = blockIdx.x * 256 + threadIdx.x;
    rp[i] = uint4{0u, 0u, 0u, 0u};   // R single plane
}

// WtT = W layout [n][256]; W2T[uv][ij*128+n]; both as hi/lo bf16 planes
__global__ void kprep(const float* __restrict__ W,
                      ushort* __restrict__ wth, ushort* __restrict__ wtl,
                      ushort* __restrict__ w2h, ushort* __restrict__ w2l) {
    int tid = blockIdx.x * 256 + threadIdx.x;   // 32768
    int n = tid >> 8, kk = tid & 255;
    ushort h, l; split2(W[tid], h, l);
    wth[tid] = h; wtl[tid] = l;
    int kx = kk >> 4, ky = kk & 15;
    int uv = (kx & 7) * 8 + (ky & 7);
    int k2 = ((kx >> 3) * 2 + (ky >> 3)) * 128 + n;
    w2h[uv * 512 + k2] = h; w2l[uv * 512 + k2] = l;
}

// t=0: resid = img (bf16) AND persistent img-bf16 plane for kconvt's epilogue
__global__ void kinit0(const float* __restrict__ img, ushort* __restrict__ rsh,
                       ushort* __restrict__ imb) {
    int t8 = (blockIdx.x * 256 + threadIdx.x) * 8;
    uint hw[4];
#pragma unroll
    for (int v = 0; v < 2; ++v) {
        float4 im = *(const float4*)&img[t8 + v * 4];
        hw[v*2+0] = pk(f2bf(im.x), f2bf(im.y));
        hw[v*2+1] = pk(f2bf(im.z), f2bf(im.w));
    }
    uint4 pkd{hw[0], hw[1], hw[2], hw[3]};
    *(uint4*)&rsh[t8] = pkd;
    *(uint4*)&imb[t8] = pkd;
}

// resid kconvt: pure-bf16 GEMM C[m=cell,uv] = R[m,512] x W2hi^T. UNGATED
// (idempotent when converged). Depth-3 prefetch, 4 LDS bufs, counted vmcnt.
// Epilogue subtracts from the bf16 img plane (half the fetch of fp32 img).
__global__ __launch_bounds__(256) void kconvt(
    const ushort* __restrict__ rp, const ushort* __restrict__ w2h,
    const ushort* __restrict__ imb, ushort* __restrict__ rsh)
{
    const int tid = threadIdx.x;
    __shared__ uint4 lds[4096];   // 4 bufs x {A[512],B[512]} = 64 KB
    const int bx = blockIdx.x;
    const int bid = ((bx & 7) << 6) | (bx >> 3);   // XCD swizzle, 512%8==0
    const int m0 = bid * 64;
    const int lane = tid & 63, w = tid >> 6;
    const int wm = w >> 1, wn = w & 1, g = lane >> 5;
    const int u = (lane & 7) ^ ((lane >> 3) & 7);   // pre-swizzled source unit

    // ---- T14 early prefetch of the epilogue img slab (bf16, 2 uint4) ----
    const int b0 = m0 >> 8;
    const int x0 = ((m0 & 255) >> 4) * 8;
    const int erow = tid >> 3, ec0 = (tid & 7) * 16;
    const int ebase = b0 * DIM * DIM + (x0 + erow) * DIM + ec0;
    uint4 ib0 = *(const uint4*)&imb[ebase];
    uint4 ib1 = *(const uint4*)&imb[ebase + 8];
    __builtin_amdgcn_sched_barrier(0);   // pin: issued before staging

    // 16 slots: s<8 A-plane rows, s>=8 B-plane rows; wave w owns s=w*4..+3
    int off0[4]; const ushort* srcp[4];
#pragma unroll
    for (int i = 0; i < 4; ++i) {
        int s = w * 4 + i;
        if (s < 8) {
            int ml = s * 8 + (lane >> 3);
            int mm = m0 + ml;
            int b_ = mm >> 8, cell = mm & 255, px0 = cell >> 4, py0 = cell & 15;
            off0[i] = ((b_ * CP + px0 + 1) * CP + py0 + 1) * NAT + u * 8;
            srcp[i] = rp;
        } else {
            int ml = (s - 8) * 8 + (lane >> 3);
            off0[i] = ml * 512 + u * 8;
            srcp[i] = w2h;
        }
    }
    auto stage = [&](int kc, int buf) {
        int ij = kc >> 1;
        int dA = (kc & 1) * 64 - ((ij >> 1) * CP + (ij & 1)) * NAT;
        int dB = kc * 64;
        uint4* base = lds + buf * 1024;
#pragma unroll
        for (int i = 0; i < 4; ++i) {
            int s = w * 4 + i;
            GLOAD16(srcp[i] + off0[i] + (s < 8 ? dA : dB), base + s * 64);
        }
    };

    f32x16 acc = {};
    const int arow = wm * 32 + (lane & 31);
    const int brow = wn * 32 + (lane & 31);
    const int ax = lane & 7;     // = arow&7 = brow&7

    stage(0, 0); stage(1, 1); stage(2, 2);
    for (int kc = 0; kc < 8; ++kc) {
        if (kc < 5) stage(kc + 3, (kc + 3) & 3);
        int nf = 7 - kc; nf = nf > 3 ? 3 : nf;    // chunks in flight past kc
        switch (nf) {
            case 3: asm volatile("s_waitcnt vmcnt(12)" ::: "memory"); break;
            case 2: asm volatile("s_waitcnt vmcnt(8)"  ::: "memory"); break;
            case 1: asm volatile("s_waitcnt vmcnt(4)"  ::: "memory"); break;
            default: asm volatile("s_waitcnt vmcnt(0)" ::: "memory"); break;
        }
        __builtin_amdgcn_s_barrier();            // chunk kc resident for all waves
        __builtin_amdgcn_sched_barrier(0);
        const uint4* Lb = lds + (kc & 3) * 1024;
#pragma unroll
        for (int ks = 0; ks < 4; ++ks) {
            int un = (ks * 2 + g) ^ ax;
            bf16x8 Ah = __builtin_bit_cast(bf16x8, Lb[      arow * 8 + un]);
            bf16x8 Bh = __builtin_bit_cast(bf16x8, Lb[512 + brow * 8 + un]);
            acc = __builtin_amdgcn_mfma_f32_32x32x16_bf16(Ah, Bh, acc, 0, 0, 0);
        }
        __builtin_amdgcn_sched_barrier(0);
        __builtin_amdgcn_s_barrier();            // buf free for overwrite
    }

    // ---- epilogue: stage 32x128 slab in LDS, write resid coalesced ----
    float* ldsO = (float*)lds;            // [32][129] fp32
    const int uvx = wn * 32 + (lane & 31);
    const int uu = uvx >> 3, vv = uvx & 7;
#pragma unroll
    for (int r = 0; r < 16; ++r) {
        int mr = m0 + wm * 32 + (r & 3) + 8 * (r >> 2) + 4 * g;
        int cl = mr & 255;
        ldsO[(((cl >> 4) & 3) * 8 + uu) * 129 + (cl & 15) * 8 + vv] = acc[r];
    }
    __syncthreads();
    const float* lrow = &ldsO[erow * 129 + ec0];
    const uint* iw0 = (const uint*)&ib0;
    const uint* iw1 = (const uint*)&ib1;
    uint hw[8];
#pragma unroll
    for (int w4 = 0; w4 < 4; ++w4) {
        hw[w4] = pk(f2bf(us2f((ushort)iw0[w4])         - lrow[2 * w4 + 0]),
                    f2bf(us2f((ushort)(iw0[w4] >> 16)) - lrow[2 * w4 + 1]));
        hw[4 + w4] = pk(f2bf(us2f((ushort)iw1[w4])         - lrow[8 + 2 * w4 + 0]),
                        f2bf(us2f((ushort)(iw1[w4] >> 16)) - lrow[8 + 2 * w4 + 1]));
    }
    *(uint4*)&rsh[ebase]     = uint4{hw[0],hw[1],hw[2],hw[3]};
    *(uint4*)&rsh[ebase + 8] = uint4{hw[4],hw[5],hw[6],hw[7]};
}

// grad: pure-bf16 GEMM g[m=64 cells, n=64 atoms] = resid[m,256] x Wthi^T.
// 2 LDS bufs (32 KB) -> 4-5 blocks/CU for TLP; depth-1 single-barrier
// schedule (stage(kc+1) after barrier kc; vmcnt(0) = exactly the needed chunk).
__global__ __launch_bounds__(256) void kgrad(
    const ushort* __restrict__ rsh, const ushort* __restrict__ wth,
    ushort* __restrict__ rp, float* __restrict__ partials, int t)
{
    __shared__ uint4 lds[2048];   // 2 bufs x {A[512],B[512]} = 32 KB
    __shared__ float red0[16];
    __shared__ int sg;
    const int tid = threadIdx.x;
    const int bx = blockIdx.x;
    const int xcd = bx & 7;   // bijective XCD swizzle for nwg=450 (q=56,r=2)
    const int bid = (xcd < 2 ? xcd * 57 : 114 + (xcd - 2) * 56) + (bx >> 3);
    const int m0 = bid * 64;
    const int n0 = blockIdx.y * 64;
    const int lane = tid & 63, w = tid >> 6;
    const int wm = w >> 1, wn = w & 1, g = lane >> 5;
    const int u = (lane & 7) ^ ((lane >> 3) & 7);
    const int pb2 = blockIdx.y * 450 + bid;
    const float* bankO = partials + ((t - 1) & 1) * 2048;
    float* bankN = partials + (t & 1) * 2048;

    // ---- early loads: gate partials (t>=1) + own-slot copy + R state ----
    float gd[4] = {0.f, 0.f, 0.f, 0.f}, gr[4] = {0.f, 0.f, 0.f, 0.f};
    float pod = 0.f, por = 0.f;
    if (t >= 1) {
#pragma unroll
        for (int k = 0; k < 4; ++k) {
            int i = tid + k * 256;
            if (i < NGRAD) { gd[k] = bankO[i]; gr[k] = bankO[1024 + i]; }
        }
        pod = bankO[pb2]; por = bankO[1024 + pb2];
    }
    int rbase0, rbase1; uint4 rv0, rv1;
    {
        int item = tid;
        int rowL = item >> 3, ch = item & 7;
        int mr = m0 + rowL;
        int bb = mr / 225, rm = mr % 225, pxx = rm / 15, pyy = rm % 15;
        rbase0 = ((bb * CP + pxx + 1) * CP + pyy + 1) * NAT + n0 + ch * 8;
        rv0 = *(const uint4*)&rp[rbase0];
    }
    {
        int item = 256 + tid;
        int rowL = item >> 3, ch = item & 7;
        int mr = m0 + rowL;
        int bb = mr / 225, rm = mr % 225, pxx = rm / 15, pyy = rm % 15;
        rbase1 = ((bb * CP + pxx + 1) * CP + pyy + 1) * NAT + n0 + ch * 8;
        rv1 = *(const uint4*)&rp[rbase1];
    }
    __builtin_amdgcn_sched_barrier(0);   // pin: all early loads precede staging

    int off0[4]; const ushort* srcp[4];
#pragma unroll
    for (int i = 0; i < 4; ++i) {
        int s = w * 4 + i;
        if (s < 8) {
            int ml = s * 8 + (lane >> 3);
            int mA = m0 + ml, bA = mA / 225, rm = mA % 225, px = rm / 15, py = rm % 15;
            off0[i] = bA * DIM * DIM + (8 * px + (u >> 1)) * DIM + 8 * py + (u & 1) * 8;
            srcp[i] = rsh;
        } else {
            int ml = (s - 8) * 8 + (lane >> 3);
            off0[i] = (n0 + ml) * 256 + u * 8;
            srcp[i] = wth;
        }
    }
    auto stage = [&](int kc, int buf) {
        uint4* base = lds + buf * 1024;
#pragma unroll
        for (int i = 0; i < 4; ++i) {
            int s = w * 4 + i;
            GLOAD16(srcp[i] + off0[i] + (s < 8 ? kc * 512 : kc * 64), base + s * 64);
        }
    };

    f32x16 acc = {};
    const int arow = wm * 32 + (lane & 31);
    const int brow = wn * 32 + (lane & 31);
    const int ax = lane & 7;

    stage(0, 0);
    for (int kc = 0; kc < 4; ++kc) {
        // only stage(kc) can be outstanding here -> wait for exactly it
        asm volatile("s_waitcnt vmcnt(0)" ::: "memory");
        __builtin_amdgcn_s_barrier();            // chunk kc resident; all waves
        __builtin_amdgcn_sched_barrier(0);       //   done computing chunk kc-1
        if (kc < 3) stage(kc + 1, (kc + 1) & 1); // overwrites buf (kc-1)&1: safe
        const uint4* Lb = lds + (kc & 1) * 1024;
#pragma unroll
        for (int ks = 0; ks < 4; ++ks) {
            int un = (ks * 2 + g) ^ ax;
            bf16x8 Ah = __builtin_bit_cast(bf16x8, Lb[      arow * 8 + un]);
            bf16x8 Bh = __builtin_bit_cast(bf16x8, Lb[512 + brow * 8 + un]);
            acc = __builtin_amdgcn_mfma_f32_32x32x16_bf16(Ah, Bh, acc, 0, 0, 0);
        }
        __builtin_amdgcn_sched_barrier(0);
    }
    __syncthreads();   // all waves done reading bufs before ldsO overlay

    // ---- finish gate decision (bit-identical order to old kconvt gate) ----
    int gate = 0;
    if (t >= 1) {
        float d2 = 0.f, r2 = 0.f;
        d2 += gd[0]; d2 += gd[1]; d2 += gd[2]; d2 += gd[3];
        r2 += gr[0]; r2 += gr[1]; r2 += gr[2]; r2 += gr[3];
        for (int off = 32; off; off >>= 1) { d2 += __shfl_down(d2, off, 64); r2 += __shfl_down(r2, off, 64); }
        int w_ = tid >> 6, l = tid & 63;
        if (l == 0) { red0[w_] = d2; red0[8 + w_] = r2; }
        __syncthreads();
        if (tid == 0) {
            float td = red0[0] + red0[1] + red0[2] + red0[3];
            float tr = red0[8] + red0[9] + red0[10] + red0[11];
            sg = (td < 1e-4f * tr) ? 1 : 0;
        }
        __syncthreads();
        gate = sg;
    }
    const bool dow = (t == 0) || (gate == 0);

    // ---- stage acc -> ldsO[64][76] (<=2-way conflicts both phases)
    float* ldsO = (float*)lds;
    {
        const int colL = wn * 32 + (lane & 31);
#pragma unroll
        for (int r = 0; r < 16; ++r) {
            int rowL = wm * 32 + (r & 3) + 8 * (r >> 2) + 4 * g;
            ldsO[rowL * 76 + colL] = acc[r];
        }
    }
    __syncthreads();

    // ---- RMW on prefetched R: 2 items/thread, 8 atoms each (gated)
    float d2 = 0.f, r2 = 0.f;
    if (dow) {
#pragma unroll
        for (int i = 0; i < 2; ++i) {
            int item = i * 256 + tid;
            int rowL = item >> 3, ch = item & 7;
            uint4 hv = i ? rv1 : rv0;
            int base = i ? rbase1 : rbase0;
            const float* lp = &ldsO[rowL * 76 + ch * 8];
            uint ho[4];
#pragma unroll
            for (int wd = 0; wd < 4; ++wd) {
                uint hw_ = ((const uint*)&hv)[wd];
                ushort nh0, nh1;
                {
                    float rold = us2f((ushort)hw_);
                    float v = fmaf(STEP, lp[wd * 2 + 0], rold);
                    float st = fmaxf(v - LMD, 0.f) - fmaxf(-v - LMD, 0.f);
                    nh0 = f2bf(st);
                    float df = us2f(nh0) - rold;      // stored-state delta
                    d2 += df * df; r2 += rold * rold;
                }
                {
                    float rold = us2f((ushort)(hw_ >> 16));
                    float v = fmaf(STEP, lp[wd * 2 + 1], rold);
                    float st = fmaxf(v - LMD, 0.f) - fmaxf(-v - LMD, 0.f);
                    nh1 = f2bf(st);
                    float df = us2f(nh1) - rold;
                    d2 += df * df; r2 += rold * rold;
                }
                ho[wd] = pk(nh0, nh1);
            }
            *(uint4*)&rp[base] = uint4{ho[0], ho[1], ho[2], ho[3]};
        }
    }

    for (int off = 32; off; off >>= 1) { d2 += __shfl_down(d2, off, 64); r2 += __shfl_down(r2, off, 64); }
    int w_ = tid >> 6, l = tid & 63;
    if (l == 0) { red0[w_] = d2; red0[8 + w_] = r2; }
    __syncthreads();
    if (tid == 0) {
        if (dow) {
            float td = red0[0] + red0[1] + red0[2] + red0[3];
            float tr = red0[8] + red0[9] + red0[10] + red0[11];
            bankN[pb2] = td;
            bankN[1024 + pb2] = tr;
        } else {   // converged: freeze partials (copy own slot forward)
            bankN[pb2] = pod;
            bankN[1024 + pb2] = por;
        }
    }
}

// final reconstruction: C = R x (W2hi + W2lo)^T, fp32 out.
__global__ __launch_bounds__(256) void kfinal(
    const ushort* __restrict__ rp,
    const ushort* __restrict__ w2h, const ushort* __restrict__ w2l,
    float* __restrict__ outp)
{
    const int tid = threadIdx.x;
    __shared__ uint4 lds[3072];   // 2 bufs x {A[512],Bh[512],Bl[512]} = 48 KB
    const int bx = blockIdx.x;
    const int bid = ((bx & 7) << 6) | (bx >> 3);
    const int m0 = bid * 64;
    const int lane = tid & 63, w = tid >> 6;
    const int wm = w >> 1, wn = w & 1, g = lane >> 5;
    const int u = (lane & 7) ^ ((lane >> 3) & 7);

    // 24 slots: 0-7 A rows, 8-15 Bh rows, 16-23 Bl rows; wave w owns w*6..+5
    const ushort* const srcs[3] = {rp, w2h, w2l};
    int off0[6]; const ushort* srcp[6];
#pragma unroll
    for (int i = 0; i < 6; ++i) {
        int j = w * 6 + i, p = j >> 3, jj = j & 7;
        int ml = jj * 8 + (lane >> 3);
        srcp[i] = srcs[p];
        if (p == 0) {
            int mm = m0 + ml;
            int b_ = mm >> 8, cell = mm & 255, px0 = cell >> 4, py0 = cell & 15;
            off0[i] = ((b_ * CP + px0 + 1) * CP + py0 + 1) * NAT + u * 8;
        } else {
            off0[i] = ml * 512 + u * 8;
        }
    }
    auto stage = [&](int kc, int buf) {
        int ij = kc >> 1;
        int dA = (kc & 1) * 64 - ((ij >> 1) * CP + (ij & 1)) * NAT;
        int dB = kc * 64;
#pragma unroll
        for (int i = 0; i < 6; ++i) {
            int j = w * 6 + i;
            GLOAD16(srcp[i] + off0[i] + (j < 8 ? dA : dB), lds + buf * 1536 + j * 64);
        }
    };

    f32x16 acc = {};
    const int arow = wm * 32 + (lane & 31);
    const int brow = wn * 32 + (lane & 31);
    const int ax = lane & 7;

    stage(0, 0);
    __syncthreads();
    for (int kc = 0;; ++kc) {
        const int cur = kc & 1;
        if (kc < 7) stage(kc + 1, cur ^ 1);
        const uint4* Lb = lds + cur * 1536;
#pragma unroll
        for (int ks = 0; ks < 4; ++ks) {
            int un = (ks * 2 + g) ^ ax;
            bf16x8 Ah = __builtin_bit_cast(bf16x8, Lb[       arow * 8 + un]);
            bf16x8 Bh = __builtin_bit_cast(bf16x8, Lb[512  + brow * 8 + un]);
            bf16x8 Bl = __builtin_bit_cast(bf16x8, Lb[1024 + brow * 8 + un]);
            acc = __builtin_amdgcn_mfma_f32_32x32x16_bf16(Ah, Bh, acc, 0, 0, 0);
            acc = __builtin_amdgcn_mfma_f32_32x32x16_bf16(Ah, Bl, acc, 0, 0, 0);
        }
        if (kc == 7) break;
        __syncthreads();
    }

    __syncthreads();
    float* ldsO = (float*)lds;
    const int uvx = wn * 32 + (lane & 31);
    const int uu = uvx >> 3, vv = uvx & 7;
#pragma unroll
    for (int r = 0; r < 16; ++r) {
        int mr = m0 + wm * 32 + (r & 3) + 8 * (r >> 2) + 4 * g;
        int cl = mr & 255;
        ldsO[(((cl >> 4) & 3) * 8 + uu) * 129 + (cl & 15) * 8 + vv] = acc[r];
    }
    __syncthreads();
    const int b0 = m0 >> 8;
    const int x0 = ((m0 & 255) >> 4) * 8;
    const int row = tid >> 3, c0 = (tid & 7) * 16;
    const int base = b0 * DIM * DIM + (x0 + row) * DIM + c0;
    const float* lrow = &ldsO[row * 129 + c0];
#pragma unroll
    for (int v = 0; v < 4; ++v)
        *(float4*)&outp[base + v * 4] =
            float4{lrow[v*4], lrow[v*4+1], lrow[v*4+2], lrow[v*4+3]};
}

extern "C" void kernel_launch(void* const* d_in, const int* in_sizes, int n_in,
                              void* d_out, int out_size, void* d_ws, size_t ws_size,
                              hipStream_t stream) {
    const float* img = (const float*)d_in[0];
    const float* W   = (const float*)d_in[1];
    char* ws = (char*)d_ws;
    ushort* rp  = (ushort*)(ws + O_RP);
    ushort* rsh = (ushort*)(ws + O_RSH);
    ushort* w2h = (ushort*)(ws + O_W2H);
    ushort* w2l = (ushort*)(ws + O_W2L);
    ushort* wth = (ushort*)(ws + O_WTH);
    ushort* wtl = (ushort*)(ws + O_WTL);
    float* partials = (float*)(ws + O_PART);
    ushort* imb = (ushort*)(ws + O_IMB);
    float* outp = (float*)d_out;

    kzero<<<2312, 256, 0, stream>>>((uint4*)(ws + O_RP));   // R plane = 9.47 MB
    kprep<<<128, 256, 0, stream>>>(W, wth, wtl, w2h, w2l);
    kinit0<<<1024, 256, 0, stream>>>(img, rsh, imb);        // resid = img; imb = bf16(img)
    kgrad<<<dim3(450, 2), 256, 0, stream>>>(rsh, wth, rp, partials, 0);
    for (int t = 1; t < MAXIT; ++t) {
        kconvt<<<512, 256, 0, stream>>>(rp, w2h, imb, rsh);
        kgrad<<<dim3(450, 2), 256, 0, stream>>>(rsh, wth, rp, partials, t);
    }
    kfinal<<<512, 256, 0, stream>>>(rp, w2h, w2l, outp);
}